// Round 1
// 198.042 us; speedup vs baseline: 1.0045x; 1.0045x over previous
//
#include <hip/hip_runtime.h>
#include <math.h>
#include <limits.h>

#define ALPHA  0.1f
#define DT     0.01f
#define EPSV   1e-9f
#define DIFF   10.0f
#define HARD_P 1.5707963267948966f

typedef int v4i __attribute__((ext_vector_type(4)));

// ---------------------------------------------------------------------------
// Kernel 1: per-node precompute (dense, cheap).
//   g[i] = e^{-i*phase[i]} * (x_i + i*y_i)
//   out[3N:5N] = xy  (xy_dot_old_new)
//   Gsum[i] = 0      (atomic target)
// ---------------------------------------------------------------------------
__global__ void node_pre(const float2* __restrict__ xy,
                         const float*  __restrict__ phase,
                         float2* __restrict__ g,
                         float2* __restrict__ out_xyold,
                         float2* __restrict__ Gsum,
                         int n) {
    int i = blockIdx.x * blockDim.x + threadIdx.x;
    if (i >= n) return;
    float2 p = xy[i];
    float ph = phase[i];
    float s, c;
    sincosf(ph, &s, &c);
    float2 gv;
    gv.x = p.x * c + p.y * s;   // e^{-i ph} * (x + iy)
    gv.y = p.y * c - p.x * s;
    g[i] = gv;
    out_xyold[i] = p;
    float2 z; z.x = 0.f; z.y = 0.f;
    Gsum[i] = z;
}

// ---------------------------------------------------------------------------
// Kernel 2: persistent, 2-deep software-pipelined segmented reduction.
// 8 edges/lane (512-edge tiles), grid-stride tiles per wave.
// Loop body: issue idx(t+2) -> issue gathers(t+1) -> compute(t).
// Natural register dataflow => compiler emits counted vmcnt waits, so
// gather latency hides under compute of the previous tile and idx-load
// latency hides under two compute phases.
// ---------------------------------------------------------------------------
#define EPL 8
#define TILE_EDGES 512   // 64 lanes * EPL

struct Idx8 { int s[EPL]; int d[EPL]; };

__device__ __forceinline__ void load_idx(Idx8& I,
                                         const int* __restrict__ src,
                                         const int* __restrict__ dst,
                                         long tile_base, int n_edges, int lane) {
    long b = tile_base + (long)lane * EPL;
    if (b + (EPL - 1) < (long)n_edges) {
        v4i s0 = __builtin_nontemporal_load((const v4i*)(src + b));
        v4i s1 = __builtin_nontemporal_load((const v4i*)(src + b + 4));
        v4i d0 = __builtin_nontemporal_load((const v4i*)(dst + b));
        v4i d1 = __builtin_nontemporal_load((const v4i*)(dst + b + 4));
        #pragma unroll
        for (int j = 0; j < 4; ++j) { I.s[j] = s0[j]; I.s[j + 4] = s1[j]; }
        #pragma unroll
        for (int j = 0; j < 4; ++j) { I.d[j] = d0[j]; I.d[j + 4] = d1[j]; }
    } else {
        #pragma unroll
        for (int j = 0; j < EPL; ++j) {
            long e = b + j;
            if (e < (long)n_edges) { I.s[j] = src[e]; I.d[j] = dst[e]; }
            else                   { I.s[j] = INT_MAX; I.d[j] = 0; }
        }
    }
}

__device__ __forceinline__ void gather_g(float gx[EPL], float gy[EPL],
                                         const float2* __restrict__ g,
                                         const Idx8& I) {
    #pragma unroll
    for (int j = 0; j < EPL; ++j) {
        float2 v = g[I.d[j]];
        gx[j] = v.x; gy[j] = v.y;
    }
}

__device__ __forceinline__ void compute_tile(const Idx8& I,
                                             const float gx[EPL],
                                             const float gy[EPL],
                                             float* __restrict__ Gsum,
                                             int lane) {
    int   sk[EPL];
    float vx[EPL], vy[EPL];
    #pragma unroll
    for (int j = 0; j < EPL; ++j) {
        sk[j] = I.s[j];
        bool valid = (sk[j] != INT_MAX);
        vx[j] = valid ? gx[j] : 0.f;
        vy[j] = valid ? gy[j] : 0.f;
    }

    // ---- local run combine (keys sorted within the tile) ----
    int   kF = sk[0], rk = sk[0];
    float fx = 0.f, fy = 0.f;            // first-run sum (once closed)
    float rx = vx[0], ry = vy[0];        // current-run sum
    bool  firstClosed = false;
    #pragma unroll
    for (int j = 1; j < EPL; ++j) {
        if (sk[j] == rk) {
            rx += vx[j]; ry += vy[j];
        } else {
            if (!firstClosed) { fx = rx; fy = ry; firstClosed = true; }
            else {
                // interior complete run (rare: needs 2+ boundaries in 8 edges)
                atomicAdd(&Gsum[2*rk],   rx);
                atomicAdd(&Gsum[2*rk+1], ry);
            }
            rk = sk[j]; rx = vx[j]; ry = vy[j];
        }
    }
    const int  kL   = rk;
    const bool pure = !firstClosed;      // whole lane one key

    // ---- wave segmented inclusive scan over (kL, suffix-sum) ----
    float ax = rx, ay = ry;
    int   key = kL;
    #pragma unroll
    for (int off = 1; off < 64; off <<= 1) {
        float px = __shfl_up(ax, off);
        float py = __shfl_up(ay, off);
        int   pk = __shfl_up(key, off);
        if (lane >= off && pk == key) { ax += px; ay += py; }
    }

    // ---- flushes ----
    float pscx = __shfl_up(ax, 1);
    float pscy = __shfl_up(ay, 1);
    int   pKL  = __shfl_up(key, 1);
    int   nKF  = __shfl_down(kF, 1);

    // (1) non-pure lane closes its first run (absorbing carry from prev lanes)
    if (!pure) {
        float gx_ = fx, gy_ = fy;
        if (lane > 0 && pKL == kF) { gx_ += pscx; gy_ += pscy; }
        atomicAdd(&Gsum[2*kF],   gx_);
        atomicAdd(&Gsum[2*kF+1], gy_);
    }
    // (2) last run ends at a lane boundary (or wave end): flush scan result
    bool endHere = (lane == 63) || (nKF != key);
    if (key != INT_MAX && endHere) {
        atomicAdd(&Gsum[2*key],   ax);
        atomicAdd(&Gsum[2*key+1], ay);
    }
}

__global__ __launch_bounds__(256, 4) void edge_seg8(
        const int*    __restrict__ src,
        const int*    __restrict__ dst,
        const float2* __restrict__ g,
        float* __restrict__ Gsum,
        int n_edges) {
    const int lane   = threadIdx.x & 63;
    const int wib    = threadIdx.x >> 6;
    const int wave   = blockIdx.x * 4 + wib;
    const int nwaves = gridDim.x * 4;
    const int n_tiles = (n_edges + TILE_EDGES - 1) / TILE_EDGES;

    int tc = wave;
    if (tc >= n_tiles) return;

    Idx8 A, B, C;
    float gax[EPL], gay[EPL], gbx[EPL], gby[EPL];

    // prologue
    load_idx(A, src, dst, (long)tc * TILE_EDGES, n_edges, lane);
    gather_g(gax, gay, g, A);                 // waits A's idx loads
    int  tn   = tc + nwaves;
    bool hasN = (tn < n_tiles);
    if (hasN) load_idx(B, src, dst, (long)tn * TILE_EDGES, n_edges, lane);

    for (;;) {
        int  tn2   = tn + nwaves;
        bool hasN2 = hasN && (tn2 < n_tiles);
        if (hasN2) load_idx(C, src, dst, (long)tn2 * TILE_EDGES, n_edges, lane);
        if (hasN)  gather_g(gbx, gby, g, B);  // waits B (in flight one full tile)
        compute_tile(A, gax, gay, Gsum, lane); // waits gathers issued last iter
        if (!hasN) break;
        A = B;
        #pragma unroll
        for (int j = 0; j < EPL; ++j) { gax[j] = gbx[j]; gay[j] = gby[j]; }
        B = C;
        tn = tn2; hasN = hasN2;
    }
}

// ---------------------------------------------------------------------------
// Kernel 3: dense per-node epilogue (1 thread/node).
// ---------------------------------------------------------------------------
__global__ void node_post(const float2* __restrict__ xy,
                          const float2* __restrict__ xyd,
                          const float*  __restrict__ phase,
                          const float*  __restrict__ w,
                          const float*  __restrict__ amps,
                          const float*  __restrict__ ha,
                          const float2* __restrict__ Gsum,
                          float* __restrict__ out,
                          int n) {
    int i = blockIdx.x * blockDim.x + threadIdx.x;
    if (i >= n) return;
    float2 p   = xy[i];
    float2 pdv = xyd[i];
    float x = p.x, y = p.y;
    float xd = pdv.x, yd = pdv.y;

    float r2 = x*x + y*y;
    float a = ALPHA * (1.0f - r2*r2);
    float h = ha[i];
    float zeta = 1.0f - h * ((xd + EPSV) / (fabsf(xd) + EPSV));
    float b = w[i] / (zeta + EPSV);
    float kx = a*x - b*y;
    float ky = b*x + a*y;

    float2 gv = Gsum[i];
    float s, c;
    sincosf(phase[i], &s, &c);
    float sumx = c*gv.x - s*gv.y;   // rotate by e^{+i*phase}
    float sumy = s*gv.x + c*gv.y;

    float xdot = fminf(fmaxf(kx + sumx, xd - DIFF), xd + DIFF);
    float ydot = fminf(fmaxf(ky + sumy, yd - DIFF), yd + DIFF);
    float xn = x + xdot * DT;
    float yn = y + ydot * DT;

    float ang = fminf(fmaxf(amps[i] * yn, -HARD_P), HARD_P);

    out[i] = ang;
    float2* xy_new = (float2*)(out + n);
    float2 v; v.x = xn; v.y = yn;
    xy_new[i] = v;
}

extern "C" void kernel_launch(void* const* d_in, const int* in_sizes, int n_in,
                              void* d_out, int out_size, void* d_ws, size_t ws_size,
                              hipStream_t stream) {
    const float2* xy    = (const float2*)d_in[0];
    const float2* xyd   = (const float2*)d_in[1];
    const float*  phase = (const float*)d_in[2];
    const float*  w     = (const float*)d_in[3];
    const float*  amps  = (const float*)d_in[4];
    const float*  ha    = (const float*)d_in[5];
    const int*    esrc  = (const int*)d_in[6];
    const int*    edst  = (const int*)d_in[7];

    const int n       = in_sizes[2];
    const int n_edges = in_sizes[6];

    float* out = (float*)d_out;

    // ws: g float2[n] | Gsum float2[n]
    float2* g    = (float2*)d_ws;
    float2* Gsum = (float2*)((char*)d_ws + (size_t)n * sizeof(float2));

    const int B = 256;
    node_pre<<<(n + B - 1) / B, B, 0, stream>>>(
        xy, phase, g, (float2*)(out + (size_t)3 * n), Gsum, n);

    // persistent pipelined edge kernel: 4 waves/block, 512 edges/tile/wave
    int n_tiles = (n_edges + TILE_EDGES - 1) / TILE_EDGES;
    int blocks  = (n_tiles + 3) / 4;
    if (blocks > 1024) blocks = 1024;   // 4 blocks/CU resident, grid-stride tiles
    if (blocks < 1)    blocks = 1;
    edge_seg8<<<blocks, B, 0, stream>>>(esrc, edst, g, (float*)Gsum, n_edges);

    node_post<<<(n + B - 1) / B, B, 0, stream>>>(
        xy, xyd, phase, w, amps, ha, Gsum, out, n);
}